// Round 12
// baseline (309.413 us; speedup 1.0000x reference)
//
#include <hip/hip_runtime.h>
#include <math.h>

// ---------------------------------------------------------------------------
// GAT 3-layer net. CSR by dst built once per call (bucketed counting sort).
// R1-R8: register softmax, bf16 gather table, counting-sort CSR build.
// R9: all-bf16 dataflow + MFMA for layers 2/3 (mfma_f32_16x16x32_bf16).
// R10: layer-1 algebraic restructure (gather raw X rows, L2-resident).
// R11: layer-3 bf16 out; k_aggx+W1-tail fusion; k_al1 in k_prep.
// R12: run-length k_pool restored.
// R13: partial-hist build (no memsets), gsum zero in prep, nt stores.
// R14: two dsts per wave in k_agg/k_aggx1 (32-lane-half softmax).
// R15: (a) k_agg wide path: fixed 32-slot gather, 2 paired batches of 8
//      unconditional loads (alpha-0 / row-0 padding) -> 8 loads in flight
//      per lane, no runtime-bounded loop (gather was latency-bound at
//      ~3.3 TB/s with VALUBusy 26%). (b) kb_scan folded into kb_hist via
//      last-block pattern: __device__ counter (module-zeroed, modulo per
//      iteration) + atomic reads of partials (device-coherent; plain
//      loads could hit stale per-XCD L2). 11 -> 10 dispatches.
// ---------------------------------------------------------------------------

#define BW 512          // nodes per bucket (power of 2)
#define PART_CHUNK 4096 // edges per WG in kb_part
#define HIST_WGS 64     // kb_hist grid (partial buffer sized to match)

typedef __attribute__((ext_vector_type(8))) short short8v;  // 8 bf16
typedef __attribute__((ext_vector_type(4))) float f32x4;
typedef __attribute__((ext_vector_type(4))) unsigned uint4v;
typedef __attribute__((ext_vector_type(2))) unsigned uint2v;

__device__ int g_hist_ctr;   // BSS: zeroed at module load; grows by HIST_WGS/iter

__device__ __forceinline__ float bflo(unsigned u) { return __uint_as_float(u << 16); }
__device__ __forceinline__ float bfhi(unsigned u) { return __uint_as_float(u & 0xffff0000u); }
// pack two f32 -> two bf16 (round-nearest-even), a in low half, b in high
__device__ __forceinline__ unsigned pk2bf(float a, float b) {
  unsigned ua = __float_as_uint(a); ua += 0x7fffu + ((ua >> 16) & 1u);
  unsigned ub = __float_as_uint(b); ub += 0x7fffu + ((ub >> 16) & 1u);
  return (ua >> 16) | (ub & 0xffff0000u);
}

// ---- CSR build, stage 1+2 fused: per-WG partial hists; last block reduces
//      (atomic reads, device-coherent) + exclusive-scans NB buckets ----
__global__ __launch_bounds__(256) void kb_hist(const int* __restrict__ ei,
                                               int* __restrict__ bpart,
                                               int* __restrict__ bbase,
                                               int* __restrict__ bcur,
                                               int* __restrict__ rowp,
                                               int E, int ET, int N, int NB) {
  __shared__ int h[128];
  __shared__ int isLast;
  int tid = threadIdx.x;
  if (tid < 128) h[tid] = 0;
  __syncthreads();
  int stride = HIST_WGS * 256;
  for (int i = blockIdx.x * 256 + tid; i < ET; i += stride) {
    int dst = (i < E) ? ei[E + i] : (i - E);
    atomicAdd(&h[dst >> 9], 1);
  }
  __syncthreads();
  if (tid < 128) bpart[blockIdx.x * 128 + tid] = h[tid];
  __threadfence();                       // release partials device-wide
  if (tid == 0) {
    int old = atomicAdd(&g_hist_ctr, 1);
    isLast = (((old + 1) % HIST_WGS) == 0) ? 1 : 0;
  }
  __syncthreads();
  if (isLast) {                          // block-uniform branch
    __shared__ int sm[128];
    int v = 0;
    if (tid < 128) {
      for (int w = 0; w < HIST_WGS; ++w)
        v += atomicAdd(&bpart[w * 128 + tid], 0);   // coherent read
      if (tid >= NB) v = 0;
      sm[tid] = v;
    }
    __syncthreads();
    for (int off = 1; off < 128; off <<= 1) {
      int u = (tid < 128 && tid >= off) ? sm[tid - off] : 0;
      __syncthreads();
      if (tid < 128) sm[tid] += u;
      __syncthreads();
    }
    if (tid < 128) {
      int pre = sm[tid] - v;             // exclusive
      if (tid <= NB) bbase[tid] = pre;   // bbase[NB] == ET
      if (tid < NB) bcur[tid] = pre;
      if (tid == 0) rowp[N] = ET;
    }
  }
}

// ---- stage 3: partition edges into bucket runs (packed src<<9|dstlocal) ----
__global__ __launch_bounds__(256) void kb_part(const int* __restrict__ ei,
                                               int* __restrict__ bcur,
                                               int* __restrict__ bucketed,
                                               int E, int ET, int NB) {
  __shared__ int hist[128];
  __shared__ int runb[128];
  int tid = threadIdx.x;
  int base = blockIdx.x * PART_CHUNK;
  if (tid < 128) hist[tid] = 0;

  int sv[16], dv[16];
#pragma unroll
  for (int k = 0; k < 16; ++k) {
    int j = base + k * 256 + tid;
    int s = -1, d = 0;
    if (j < ET) {
      if (j < E) { s = ei[j]; d = ei[E + j]; }
      else       { s = j - E; d = j - E; }
    }
    sv[k] = s; dv[k] = d;
  }
  __syncthreads();
#pragma unroll
  for (int k = 0; k < 16; ++k)
    if (sv[k] >= 0) atomicAdd(&hist[dv[k] >> 9], 1);
  __syncthreads();
  if (tid < NB && hist[tid] > 0) runb[tid] = atomicAdd(&bcur[tid], hist[tid]);
  __syncthreads();
  if (tid < 128) hist[tid] = 0;   // reuse as within-run cursor
  __syncthreads();
#pragma unroll
  for (int k = 0; k < 16; ++k) {
    if (sv[k] >= 0) {
      int b = dv[k] >> 9;
      int off = atomicAdd(&hist[b], 1);
      bucketed[runb[b] + off] = (sv[k] << 9) | (dv[k] & (BW - 1));
    }
  }
}

// ---- stage 4 + prep, merged. blocks [0,NB): per-bucket counting sort;
//      [NB,NB+64): bf16 col-major W2/W3; NB+64: layer-1 al vecs;
//      [NB+65,NB+98): zero gsum+gcnt ----
__global__ __launch_bounds__(256) void kb_csrprep(const int* __restrict__ bucketed,
                                                  const int* __restrict__ bbase,
                                                  int* __restrict__ rowp,
                                                  int* __restrict__ csr,
                                                  const float* __restrict__ W2,
                                                  const float* __restrict__ W3,
                                                  const float* __restrict__ W1,
                                                  const float* __restrict__ as1,
                                                  const float* __restrict__ ad1,
                                                  unsigned short* __restrict__ Wcm2,
                                                  unsigned short* __restrict__ Wcm3,
                                                  float* __restrict__ wv,
                                                  float* __restrict__ gsum,
                                                  int N, int NB) {
  int tid = threadIdx.x;
  if ((int)blockIdx.x >= NB) {
    int pb = blockIdx.x - NB;
    if (pb >= 65) {     // zero gsum (8192) + gcnt (64), contiguous
      int idx = (pb - 65) * 256 + tid;
      if (idx < 64 * 128 + 64) gsum[idx] = 0.f;
      return;
    }
    if (pb == 64) {     // wv[0..3]=W1@as1, wv[4..7]=W1@ad1
      if (tid >= 64) return;
      float2 a = *(const float2*)(as1 + tid * 2);
      float2 d = *(const float2*)(ad1 + tid * 2);
      float ps[4], pd[4];
#pragma unroll
      for (int k = 0; k < 4; ++k) {
        float2 w = *(const float2*)(W1 + k * 128 + tid * 2);
        ps[k] = w.x * a.x + w.y * a.y;
        pd[k] = w.x * d.x + w.y * d.y;
      }
      for (int off = 32; off; off >>= 1) {
#pragma unroll
        for (int k = 0; k < 4; ++k) {
          ps[k] += __shfl_xor(ps[k], off);
          pd[k] += __shfl_xor(pd[k], off);
        }
      }
      if (tid == 0) {
#pragma unroll
        for (int k = 0; k < 4; ++k) { wv[k] = ps[k]; wv[4 + k] = pd[k]; }
      }
      return;
    }
    int i = pb * 256 + tid;   // 16384 = 128*128
    if (i < 16384) {
      int k = i >> 7, n = i & 127;
      unsigned u = __float_as_uint(W2[i]); u += 0x7fffu + ((u >> 16) & 1u);
      Wcm2[n * 128 + k] = (unsigned short)(u >> 16);
      unsigned v = __float_as_uint(W3[i]); v += 0x7fffu + ((v >> 16) & 1u);
      Wcm3[n * 128 + k] = (unsigned short)(v >> 16);
    }
    return;
  }
  // per-bucket counting sort
  __shared__ int h[512];
  __shared__ int sm[256];
  __shared__ int cur[512];
  int b = blockIdx.x;
  int cb = bbase[b], ce = bbase[b + 1];

  h[tid] = 0; h[tid + 256] = 0;
  __syncthreads();
  for (int j = cb + tid; j < ce; j += 256)
    atomicAdd(&h[bucketed[j] & (BW - 1)], 1);
  __syncthreads();
  int a0 = h[2 * tid], a1 = h[2 * tid + 1];
  int s = a0 + a1;
  sm[tid] = s;
  __syncthreads();
  for (int off = 1; off < 256; off <<= 1) {
    int u = (tid >= off) ? sm[tid - off] : 0;
    __syncthreads();
    sm[tid] += u;
    __syncthreads();
  }
  int pre = sm[tid] - s;                 // exclusive over pairs
  cur[2 * tid] = pre;
  cur[2 * tid + 1] = pre + a0;
  __syncthreads();
  int node0 = b * BW;
  for (int local = tid; local < BW; local += 256) {
    int node = node0 + local;
    if (node < N) rowp[node] = cb + cur[local];   // coalesced segment write
  }
  __syncthreads();
  for (int j = cb + tid; j < ce; j += 256) {
    int p = bucketed[j];
    int loc = p & (BW - 1);
    int pos = cb + atomicAdd(&cur[loc], 1);
    csr[pos] = (unsigned)p >> 9;          // confined to [cb,ce) window
  }
}

// ---- full-wave (64-lane) fallback bodies ----
__device__ __forceinline__ void agg_full64(int beg, int end, float ald, int dst,
    const int* __restrict__ csr_src, const float* __restrict__ al_s,
    const uint4* __restrict__ Hbf, const float* __restrict__ bias,
    float* __restrict__ exw, unsigned* __restrict__ Ybf, int relu) {
  int lane = threadIdx.x & 63;
  int deg = end - beg;
  int q = lane >> 4, l = lane & 15;
  float acc[8];
#pragma unroll
  for (int c = 0; c < 8; ++c) acc[c] = 0.f;

  if (deg <= 64) {
    int srcv = 0;
    float e = -INFINITY;
    if (lane < deg) {
      srcv = csr_src[beg + lane];
      e = al_s[srcv] + ald;
      e = (e > 0.f) ? e : 0.2f * e;
    }
    float m = e;
    for (int off = 32; off; off >>= 1) m = fmaxf(m, __shfl_xor(m, off));
    float av = (lane < deg) ? __expf(e - m) : 0.f;
    float den = av;
    for (int off = 32; off; off >>= 1) den += __shfl_xor(den, off);
    av *= 1.0f / (den + 1e-16f);
    for (int t = 0; t < deg; t += 4) {      // padded slots have av=0
      int sA = __shfl(srcv, t + q);
      float wA = __shfl(av, t + q);
      uint4 va = Hbf[(size_t)sA * 16 + l];
      acc[0] += wA * bflo(va.x); acc[1] += wA * bfhi(va.x);
      acc[2] += wA * bflo(va.y); acc[3] += wA * bfhi(va.y);
      acc[4] += wA * bflo(va.z); acc[5] += wA * bfhi(va.z);
      acc[6] += wA * bflo(va.w); acc[7] += wA * bfhi(va.w);
    }
  } else {
    float m = -INFINITY;
    for (int j = beg + lane; j < end; j += 64) {
      float e = al_s[csr_src[j]] + ald;
      e = (e > 0.f) ? e : 0.2f * e;
      exw[j] = e;
      m = fmaxf(m, e);
    }
    for (int off = 32; off; off >>= 1) m = fmaxf(m, __shfl_xor(m, off));
    float den = 0.f;
    for (int j = beg + lane; j < end; j += 64) {
      float ex = __expf(exw[j] - m);
      exw[j] = ex;
      den += ex;
    }
    for (int off = 32; off; off >>= 1) den += __shfl_xor(den, off);
    float inv = 1.0f / (den + 1e-16f);
    for (int j = beg + q; j < end; j += 4) {
      int sA = csr_src[j];
      float wA = exw[j] * inv;
      uint4 va = Hbf[(size_t)sA * 16 + l];
      acc[0] += wA * bflo(va.x); acc[1] += wA * bfhi(va.x);
      acc[2] += wA * bflo(va.y); acc[3] += wA * bfhi(va.y);
      acc[4] += wA * bflo(va.z); acc[5] += wA * bfhi(va.z);
      acc[6] += wA * bflo(va.w); acc[7] += wA * bfhi(va.w);
    }
  }
#pragma unroll
  for (int c = 0; c < 8; ++c) {
    acc[c] += __shfl_xor(acc[c], 16);
    acc[c] += __shfl_xor(acc[c], 32);
  }
  if (q == 0) {
    float4 bv0 = *(const float4*)(bias + l * 8);
    float4 bv1 = *(const float4*)(bias + l * 8 + 4);
    float o0 = acc[0] + bv0.x, o1 = acc[1] + bv0.y, o2 = acc[2] + bv0.z, o3 = acc[3] + bv0.w;
    float o4 = acc[4] + bv1.x, o5 = acc[5] + bv1.y, o6 = acc[6] + bv1.z, o7 = acc[7] + bv1.w;
    if (relu) {
      o0 = fmaxf(o0, 0.f); o1 = fmaxf(o1, 0.f); o2 = fmaxf(o2, 0.f); o3 = fmaxf(o3, 0.f);
      o4 = fmaxf(o4, 0.f); o5 = fmaxf(o5, 0.f); o6 = fmaxf(o6, 0.f); o7 = fmaxf(o7, 0.f);
    }
    uint4v pb;
    pb.x = pk2bf(o0, o1); pb.y = pk2bf(o2, o3);
    pb.z = pk2bf(o4, o5); pb.w = pk2bf(o6, o7);
    __builtin_nontemporal_store(pb, (uint4v*)(Ybf + (size_t)dst * 64 + l * 4));
  }
}

__device__ __forceinline__ void aggx1_full64(int beg, int end, float ald, int dst,
    const int* __restrict__ csr_src, const float* __restrict__ X,
    float wvs0, float wvs1, float wvs2, float wvs3,
    const float* __restrict__ W, const float* __restrict__ bias,
    float* __restrict__ exw, unsigned* __restrict__ Ybf) {
  int lane = threadIdx.x & 63;
  int deg = end - beg;
  float4 acc = {0.f, 0.f, 0.f, 0.f};
  if (deg <= 64) {
    int srcv = 0;
    float e = -INFINITY;
    float4 xv = {0.f, 0.f, 0.f, 0.f};
    if (lane < deg) {
      srcv = csr_src[beg + lane];
      xv = *(const float4*)(X + (size_t)srcv * 4);
      e = xv.x * wvs0 + xv.y * wvs1 + xv.z * wvs2 + xv.w * wvs3 + ald;
      e = (e > 0.f) ? e : 0.2f * e;
    }
    float m = e;
    for (int off = 32; off; off >>= 1) m = fmaxf(m, __shfl_xor(m, off));
    float av = (lane < deg) ? __expf(e - m) : 0.f;
    float den = av;
    for (int off = 32; off; off >>= 1) den += __shfl_xor(den, off);
    av *= 1.0f / (den + 1e-16f);
    acc.x = av * xv.x; acc.y = av * xv.y; acc.z = av * xv.z; acc.w = av * xv.w;
  } else {
    float m = -INFINITY;
    for (int j = beg + lane; j < end; j += 64) {
      int s = csr_src[j];
      float4 xv = *(const float4*)(X + (size_t)s * 4);
      float e = xv.x * wvs0 + xv.y * wvs1 + xv.z * wvs2 + xv.w * wvs3 + ald;
      e = (e > 0.f) ? e : 0.2f * e;
      exw[j] = e;
      m = fmaxf(m, e);
    }
    for (int off = 32; off; off >>= 1) m = fmaxf(m, __shfl_xor(m, off));
    float den = 0.f;
    for (int j = beg + lane; j < end; j += 64) {
      float ex = __expf(exw[j] - m);
      exw[j] = ex;
      den += ex;
    }
    for (int off = 32; off; off >>= 1) den += __shfl_xor(den, off);
    float inv = 1.0f / (den + 1e-16f);
    for (int j = beg + lane; j < end; j += 64) {
      int s = csr_src[j];
      float w = exw[j] * inv;
      float4 xv = *(const float4*)(X + (size_t)s * 4);
      acc.x += w * xv.x; acc.y += w * xv.y; acc.z += w * xv.z; acc.w += w * xv.w;
    }
  }
  for (int off = 32; off; off >>= 1) {
    acc.x += __shfl_xor(acc.x, off);
    acc.y += __shfl_xor(acc.y, off);
    acc.z += __shfl_xor(acc.z, off);
    acc.w += __shfl_xor(acc.w, off);
  }
  int f = lane * 2;
  float2 w0 = *(const float2*)(W + f);
  float2 w1 = *(const float2*)(W + 128 + f);
  float2 w2 = *(const float2*)(W + 256 + f);
  float2 w3 = *(const float2*)(W + 384 + f);
  float2 bv = *(const float2*)(bias + f);
  float h0 = acc.x * w0.x + acc.y * w1.x + acc.z * w2.x + acc.w * w3.x + bv.x;
  float h1 = acc.x * w0.y + acc.y * w1.y + acc.z * w2.y + acc.w * w3.y + bv.y;
  h0 = fmaxf(h0, 0.f); h1 = fmaxf(h1, 0.f);
  __builtin_nontemporal_store(pk2bf(h0, h1), Ybf + (size_t)dst * 64 + lane);
}

// ---- layer-1 fused agg + tail gemm, TWO dsts per wave (deg<=32 wide path) ----
__global__ __launch_bounds__(256) void k_aggx1(const int* __restrict__ csr_src,
                                               const int* __restrict__ rowp,
                                               const float* __restrict__ wv,
                                               const float* __restrict__ X,
                                               const float* __restrict__ W,
                                               const float* __restrict__ bias,
                                               float* __restrict__ exw,
                                               unsigned* __restrict__ Ybf, int N) {
  int wid = threadIdx.x >> 6, lane = threadIdx.x & 63;
  int half = lane >> 5, il = lane & 31;
  int d0 = blockIdx.x * 8 + wid * 2;
  if (d0 >= N) return;
  float wvs0 = wv[0], wvs1 = wv[1], wvs2 = wv[2], wvs3 = wv[3];
  float wvd0 = wv[4], wvd1 = wv[5], wvd2 = wv[6], wvd3 = wv[7];

  int dst = d0 + half;
  bool vdst = dst < N;
  int beg = 0, end = 0;
  if (vdst) { beg = rowp[dst]; end = rowp[dst + 1]; }
  int deg = end - beg;
  int mx = max(deg, __shfl_xor(deg, 32));   // wave-uniform

  float ald = 0.f;
  if (vdst) {
    float4 xd = *(const float4*)(X + (size_t)dst * 4);
    ald = xd.x * wvd0 + xd.y * wvd1 + xd.z * wvd2 + xd.w * wvd3;
  }

  if (mx <= 32) {
    int srcv = 0;
    float e = -INFINITY;
    float4 xv = {0.f, 0.f, 0.f, 0.f};
    if (il < deg) {
      srcv = csr_src[beg + il];
      xv = *(const float4*)(X + (size_t)srcv * 4);
      float e0 = xv.x * wvs0 + xv.y * wvs1 + xv.z * wvs2 + xv.w * wvs3 + ald;
      e = (e0 > 0.f) ? e0 : 0.2f * e0;
    }
    float m = e;
    for (int off = 16; off; off >>= 1) m = fmaxf(m, __shfl_xor(m, off));
    float av = (il < deg) ? __expf(e - m) : 0.f;
    float den = av;
    for (int off = 16; off; off >>= 1) den += __shfl_xor(den, off);
    av *= 1.0f / (den + 1e-16f);
    float4 acc;
    acc.x = av * xv.x; acc.y = av * xv.y; acc.z = av * xv.z; acc.w = av * xv.w;
    for (int off = 16; off; off >>= 1) {   // reduce within half
      acc.x += __shfl_xor(acc.x, off);
      acc.y += __shfl_xor(acc.y, off);
      acc.z += __shfl_xor(acc.z, off);
      acc.w += __shfl_xor(acc.w, off);
    }
    // tail gemm: half's 32 lanes each produce 4 of 128 features
    int f = il * 4;
    float4 w0 = *(const float4*)(W + f);
    float4 w1 = *(const float4*)(W + 128 + f);
    float4 w2 = *(const float4*)(W + 256 + f);
    float4 w3 = *(const float4*)(W + 384 + f);
    float4 bv = *(const float4*)(bias + f);
    float h0 = acc.x * w0.x + acc.y * w1.x + acc.z * w2.x + acc.w * w3.x + bv.x;
    float h1 = acc.x * w0.y + acc.y * w1.y + acc.z * w2.y + acc.w * w3.y + bv.y;
    float h2 = acc.x * w0.z + acc.y * w1.z + acc.z * w2.z + acc.w * w3.z + bv.z;
    float h3 = acc.x * w0.w + acc.y * w1.w + acc.z * w2.w + acc.w * w3.w + bv.w;
    h0 = fmaxf(h0, 0.f); h1 = fmaxf(h1, 0.f);
    h2 = fmaxf(h2, 0.f); h3 = fmaxf(h3, 0.f);
    if (vdst) {
      uint2v pb;
      pb.x = pk2bf(h0, h1); pb.y = pk2bf(h2, h3);
      __builtin_nontemporal_store(pb, (uint2v*)(Ybf + (size_t)dst * 64 + il * 2));
    }
  } else {
    for (int k = 0; k < 2; ++k) {          // rare: full-wave per dst
      int d = d0 + k;
      if (d < N) {
        int b = rowp[d], en = rowp[d + 1];
        float4 xd = *(const float4*)(X + (size_t)d * 4);
        float a2 = xd.x * wvd0 + xd.y * wvd1 + xd.z * wvd2 + xd.w * wvd3;
        aggx1_full64(b, en, a2, d, csr_src, X, wvs0, wvs1, wvs2, wvs3, W, bias, exw, Ybf);
      }
    }
  }
}

// MFMA GEMM: Xbf [N,128] bf16 @ Wcm [128,128] bf16 (col-major) -> Hbf bf16,
// fused al epilogue. One wave per 16 rows; 8 col-frags x 4 k-tiles of
// mfma_f32_16x16x32_bf16. C layout: col=lane&15, row=(lane>>4)*4+reg.
__global__ __launch_bounds__(256) void k_gemm128mfma(
    const unsigned short* __restrict__ Xbf,
    const unsigned short* __restrict__ Wcm,
    const float* __restrict__ asv, const float* __restrict__ adv,
    unsigned* __restrict__ Hbf,
    float* __restrict__ al_s, float* __restrict__ al_d, int N) {
  int wid = threadIdx.x >> 6, lane = threadIdx.x & 63;
  int c = lane & 15, g = lane >> 4;
  int row0 = blockIdx.x * 64 + wid * 16;
  int arow = row0 + c;
  int arowc = (arow < N) ? arow : (N - 1);

  short8v a[4];
#pragma unroll
  for (int kt = 0; kt < 4; ++kt)
    a[kt] = *(const short8v*)(Xbf + (size_t)arowc * 128 + kt * 32 + g * 8);

  f32x4 acc[8];
#pragma unroll
  for (int f = 0; f < 8; ++f) acc[f] = (f32x4){0.f, 0.f, 0.f, 0.f};

#pragma unroll
  for (int f = 0; f < 8; ++f) {
    const unsigned short* wb = Wcm + (size_t)(f * 16 + c) * 128 + g * 8;
#pragma unroll
    for (int kt = 0; kt < 4; ++kt) {
      short8v b = *(const short8v*)(wb + kt * 32);
      acc[f] = __builtin_amdgcn_mfma_f32_16x16x32_bf16(a[kt], b, acc[f], 0, 0, 0);
    }
  }

  // al epilogue: ps/pd per row, reduce across the 16 col-lanes
  float ps[4] = {0.f, 0.f, 0.f, 0.f}, pd[4] = {0.f, 0.f, 0.f, 0.f};
#pragma unroll
  for (int f = 0; f < 8; ++f) {
    float as_c = asv[f * 16 + c], ad_c = adv[f * 16 + c];
#pragma unroll
    for (int j = 0; j < 4; ++j) { ps[j] += acc[f][j] * as_c; pd[j] += acc[f][j] * ad_c; }
  }
#pragma unroll
  for (int j = 0; j < 4; ++j) {
    for (int off = 1; off < 16; off <<= 1) {
      ps[j] += __shfl_xor(ps[j], off);
      pd[j] += __shfl_xor(pd[j], off);
    }
  }
  if (c == 0) {
#pragma unroll
    for (int j = 0; j < 4; ++j) {
      int r = row0 + g * 4 + j;
      if (r < N) { al_s[r] = ps[j]; al_d[r] = pd[j]; }
    }
  }

  // bf16 store: pair adjacent cols via shfl (uniform exec), even lanes store u32
#pragma unroll
  for (int f = 0; f < 8; ++f) {
#pragma unroll
    for (int j = 0; j < 4; ++j) {
      float partner = __shfl_xor(acc[f][j], 1);
      int r = row0 + g * 4 + j;
      if (((lane & 1) == 0) && r < N)
        __builtin_nontemporal_store(pk2bf(acc[f][j], partner),
                                    Hbf + (size_t)r * 64 + f * 8 + (c >> 1));
    }
  }
}

// per-dst softmax + aggregation, TWO dsts per wave (deg<=32 wide path).
// Wide path: fixed 32-slot gather, 2 paired batches of 8 unconditional
// loads (padded slots: alpha=0, srcv=0 -> row-0 re-read, exact zero
// contribution) -> 8 independent loads in flight per lane, no runtime
// loop. Rare deg>32: full-wave path. bf16 Y out (nt).
__global__ __launch_bounds__(256) void k_agg(const int* __restrict__ csr_src,
                                             const int* __restrict__ rowp,
                                             const float* __restrict__ al_s,
                                             const float* __restrict__ al_d,
                                             const uint4* __restrict__ Hbf,
                                             const float* __restrict__ bias,
                                             float* __restrict__ exw,
                                             unsigned* __restrict__ Ybf,
                                             int N, int relu) {
  int wid = threadIdx.x >> 6, lane = threadIdx.x & 63;
  int half = lane >> 5, il = lane & 31;
  int d0 = blockIdx.x * 8 + wid * 2;
  if (d0 >= N) return;
  int dst = d0 + half;
  bool vdst = dst < N;
  int beg = 0, end = 0;
  if (vdst) { beg = rowp[dst]; end = rowp[dst + 1]; }
  int deg = end - beg;
  int mx = max(deg, __shfl_xor(deg, 32));   // wave-uniform
  float ald = vdst ? al_d[dst] : 0.f;

  if (mx <= 32) {
    int srcv = 0;
    float e = -INFINITY;
    if (il < deg) {
      srcv = csr_src[beg + il];
      e = al_s[srcv] + ald;
      e = (e > 0.f) ? e : 0.2f * e;
    }
    float m = e;
    for (int off = 16; off; off >>= 1) m = fmaxf(m, __shfl_xor(m, off));
    float av = (il < deg) ? __expf(e - m) : 0.f;
    float den = av;
    for (int off = 16; off; off >>= 1) den += __shfl_xor(den, off);
    av *= 1.0f / (den + 1e-16f);   // alpha (0 for padded slots)

    int q = il >> 4, l = il & 15;
    int b32 = lane & 32;
    float acc[8];
#pragma unroll
    for (int c = 0; c < 8; ++c) acc[c] = 0.f;

    // two paired batches of 8 edges (slots: base + {0,2,4,6,8,10,12,14} + q)
#pragma unroll
    for (int gbase = 0; gbase < 32; gbase += 16) {
      int s[8]; float w[8];
#pragma unroll
      for (int k = 0; k < 8; ++k) {
        int slot = b32 + gbase + k * 2 + q;
        s[k] = __shfl(srcv, slot);
        w[k] = __shfl(av, slot);
      }
      uint4 v[8];
#pragma unroll
      for (int k = 0; k < 8; ++k) v[k] = Hbf[(size_t)s[k] * 16 + l];
#pragma unroll
      for (int k = 0; k < 8; ++k) {
        acc[0] += w[k] * bflo(v[k].x); acc[1] += w[k] * bfhi(v[k].x);
        acc[2] += w[k] * bflo(v[k].y); acc[3] += w[k] * bfhi(v[k].y);
        acc[4] += w[k] * bflo(v[k].z); acc[5] += w[k] * bfhi(v[k].z);
        acc[6] += w[k] * bflo(v[k].w); acc[7] += w[k] * bfhi(v[k].w);
      }
    }
#pragma unroll
    for (int c = 0; c < 8; ++c) acc[c] += __shfl_xor(acc[c], 16);  // quarters
    if (q == 0 && vdst) {
      float4 bv0 = *(const float4*)(bias + l * 8);
      float4 bv1 = *(const float4*)(bias + l * 8 + 4);
      float o0 = acc[0] + bv0.x, o1 = acc[1] + bv0.y, o2 = acc[2] + bv0.z, o3 = acc[3] + bv0.w;
      float o4 = acc[4] + bv1.x, o5 = acc[5] + bv1.y, o6 = acc[6] + bv1.z, o7 = acc[7] + bv1.w;
      if (relu) {
        o0 = fmaxf(o0, 0.f); o1 = fmaxf(o1, 0.f); o2 = fmaxf(o2, 0.f); o3 = fmaxf(o3, 0.f);
        o4 = fmaxf(o4, 0.f); o5 = fmaxf(o5, 0.f); o6 = fmaxf(o6, 0.f); o7 = fmaxf(o7, 0.f);
      }
      uint4v pb;
      pb.x = pk2bf(o0, o1); pb.y = pk2bf(o2, o3);
      pb.z = pk2bf(o4, o5); pb.w = pk2bf(o6, o7);
      __builtin_nontemporal_store(pb, (uint4v*)(Ybf + (size_t)dst * 64 + l * 4));
    }
  } else {
    for (int k = 0; k < 2; ++k) {          // rare: full-wave per dst
      int d = d0 + k;
      if (d < N) {
        int b = rowp[d], en = rowp[d + 1];
        agg_full64(b, en, al_d[d], d, csr_src, al_s, Hbf, bias, exw, Ybf, relu);
      }
    }
  }
}

// run-length pooling over sorted batch, bf16 input (lane owns feats 2l,2l+1)
__global__ __launch_bounds__(256) void k_pool(const unsigned* __restrict__ Ybf,
                                              const int* __restrict__ batch,
                                              float* __restrict__ gsum,
                                              float* __restrict__ gcnt,
                                              int N, int nwaves) {
  int gw = (blockIdx.x * 256 + threadIdx.x) >> 6;
  int lane = threadIdx.x & 63;
  int chunk = (N + nwaves - 1) / nwaves;
  int beg = gw * chunk;
  int end = beg + chunk; if (end > N) end = N;
  if (beg >= end) return;

  int curg = batch[beg];
  float2 acc = {0.f, 0.f};
  int cnt = 0;
  for (int n = beg; n < end; ++n) {
    int g = batch[n];
    if (g != curg) {
      atomicAdd(&gsum[curg * 128 + lane * 2], acc.x);
      atomicAdd(&gsum[curg * 128 + lane * 2 + 1], acc.y);
      if (lane == 0) atomicAdd(&gcnt[curg], (float)cnt);
      acc.x = 0.f; acc.y = 0.f; cnt = 0; curg = g;
    }
    unsigned u = Ybf[(size_t)n * 64 + lane];
    acc.x += bflo(u); acc.y += bfhi(u);
    ++cnt;
  }
  atomicAdd(&gsum[curg * 128 + lane * 2], acc.x);
  atomicAdd(&gsum[curg * 128 + lane * 2 + 1], acc.y);
  if (lane == 0) atomicAdd(&gcnt[curg], (float)cnt);
}

__global__ __launch_bounds__(128) void k_final(const float* __restrict__ gsum,
                                               const float* __restrict__ gcnt,
                                               const float* __restrict__ Wlin,
                                               const float* __restrict__ blin,
                                               float* __restrict__ out) {
  int t = threadIdx.x;  // 128 threads: (g, c) pairs
  int g = t >> 1, c = t & 1;
  float inv = 1.0f / fmaxf(gcnt[g], 1.0f);
  float acc = blin[c];
  for (int k = 0; k < 128; ++k) acc += gsum[g * 128 + k] * inv * Wlin[k * 2 + c];
  out[g * 2 + c] = acc;
}

extern "C" void kernel_launch(void* const* d_in, const int* in_sizes, int n_in,
                              void* d_out, int out_size, void* d_ws, size_t ws_size,
                              hipStream_t stream) {
  const float* x    = (const float*)d_in[0];
  const int*   ei   = (const int*)d_in[1];
  const int*   batch= (const int*)d_in[2];
  const float* W1   = (const float*)d_in[3];
  const float* as1  = (const float*)d_in[4];
  const float* ad1  = (const float*)d_in[5];
  const float* b1   = (const float*)d_in[6];
  const float* W2   = (const float*)d_in[7];
  const float* as2  = (const float*)d_in[8];
  const float* ad2  = (const float*)d_in[9];
  const float* b2   = (const float*)d_in[10];
  const float* W3   = (const float*)d_in[11];
  const float* as3  = (const float*)d_in[12];
  const float* ad3  = (const float*)d_in[13];
  const float* b3   = (const float*)d_in[14];
  const float* Wlin = (const float*)d_in[15];
  const float* blin = (const float*)d_in[16];

  int N = in_sizes[0] / 4;
  int E = in_sizes[1] / 2;
  int ET = E + N;
  int NB = (N + BW - 1) / BW;   // buckets (<=128 for N<=65536)

  char* ws = (char*)d_ws;
  unsigned* bfA = (unsigned*)ws; ws += (size_t)N * 64 * 4;   // bf16 H table
  unsigned* bfB = (unsigned*)ws; ws += (size_t)N * 64 * 4;   // bf16 Y table
  float* al_s = (float*)ws; ws += (size_t)N * 4;
  float* al_d = (float*)ws; ws += (size_t)N * 4;
  float* wv   = (float*)ws; ws += (size_t)64 * 4;            // layer-1 al vecs
  float* gsum = (float*)ws; ws += (size_t)64 * 128 * 4;
  float* gcnt = (float*)ws; ws += (size_t)64 * 4;
  int* rowp   = (int*)ws;   ws += (size_t)(N + 1) * 4;
  int* csr    = (int*)ws;   ws += (size_t)ET * 4;
  float* exw  = (float*)ws; ws += (size_t)ET * 4;
  int* bucketed = (int*)ws; ws += (size_t)ET * 4;
  int* bpart  = (int*)ws;   ws += (size_t)HIST_WGS * 128 * 4;
  int* bbase  = (int*)ws;   ws += (size_t)132 * 4;
  int* bcur   = (int*)ws;   ws += (size_t)128 * 4;
  unsigned short* wcm2 = (unsigned short*)ws; ws += (size_t)128 * 128 * 2;
  unsigned short* wcm3 = (unsigned short*)ws; ws += (size_t)128 * 128 * 2;

  // CSR build (bucketed counting sort) + merged prep (no memsets)
  kb_hist<<<HIST_WGS, 256, 0, stream>>>(ei, bpart, bbase, bcur, rowp, E, ET, N, NB);
  kb_part<<<(ET + PART_CHUNK - 1) / PART_CHUNK, 256, 0, stream>>>(ei, bcur, bucketed, E, ET, NB);
  kb_csrprep<<<NB + 98, 256, 0, stream>>>(bucketed, bbase, rowp, csr,
                                          W2, W3, W1, as1, ad1, wcm2, wcm3, wv, gsum, N, NB);

  int nb8 = (N + 7) / 8;
  int nb64 = (N + 63) / 64;
  // layer 1: fused al + gather-X + W1 tail (2 dsts/wave)
  k_aggx1<<<nb8, 256, 0, stream>>>(csr, rowp, wv, x, W1, b1, exw, bfB, N);
  // layer 2
  k_gemm128mfma<<<nb64, 256, 0, stream>>>((const unsigned short*)bfB, wcm2, as2, ad2, bfA, al_s, al_d, N);
  k_agg        <<<nb8, 256, 0, stream>>>(csr, rowp, al_s, al_d, (const uint4*)bfA, b2, exw, bfB, N, 1);
  // layer 3
  k_gemm128mfma<<<nb64, 256, 0, stream>>>((const unsigned short*)bfB, wcm3, as3, ad3, bfA, al_s, al_d, N);
  k_agg        <<<nb8, 256, 0, stream>>>(csr, rowp, al_s, al_d, (const uint4*)bfA, b3, exw, bfB, N, 0);

  // run-length pool (1024 waves) + linear head
  k_pool <<<256, 256, 0, stream>>>(bfB, batch, gsum, gcnt, N, 1024);
  k_final<<<1, 128, 0, stream>>>(gsum, gcnt, Wlin, blin, (float*)d_out);
}